// Round 7
// baseline (153.043 us; speedup 1.0000x reference)
//
#include <hip/hip_runtime.h>
#include <cstdint>

#define BDIM 4
#define SEQ 2048
#define DMODEL 1024
#define NH 16
#define HDIM 64

typedef __attribute__((ext_vector_type(8))) short bf16x8;
typedef __attribute__((ext_vector_type(4))) float f32x4;
typedef __attribute__((ext_vector_type(4))) int i32x4;
typedef __attribute__((ext_vector_type(4))) unsigned short u16x4;

#define MFMA16(a, b, c) __builtin_amdgcn_mfma_f32_16x16x32_bf16(a, b, c, 0, 0, 0)

__device__ __forceinline__ unsigned short f2bf(float x) {
    unsigned int u = __float_as_uint(x);
    unsigned int r = (u + 0x7FFFu + ((u >> 16) & 1u)) >> 16;
    return (unsigned short)r;
}

__device__ __forceinline__ void gload16(const void* g, void* l) {
    __builtin_amdgcn_global_load_lds(
        (const __attribute__((address_space(1))) unsigned int*)g,
        (__attribute__((address_space(3))) unsigned int*)l, 16, 0, 0);
}

// ---------------- convert fp32 -> bf16 ----------------
__global__ __launch_bounds__(256) void k_cvt_x(const float* __restrict__ src,
                                               unsigned short* __restrict__ dst) {
    int i = blockIdx.x * 256 + threadIdx.x;  // n4 = 2097152 exact
    float4 v = ((const float4*)src)[i];
    u16x4 o = {f2bf(v.x), f2bf(v.y), f2bf(v.z), f2bf(v.w)};
    ((u16x4*)dst)[i] = o;
}

__global__ __launch_bounds__(256) void k_cvt_w(const float* __restrict__ wq,
                                               const float* __restrict__ wk,
                                               const float* __restrict__ wv,
                                               unsigned short* __restrict__ dst) {
    int i = blockIdx.x * 256 + threadIdx.x;  // 786432 exact
    int e = i << 2;
    int which = e >> 20;
    int off = e & 0xFFFFF;
    const float* s = which == 0 ? wq : (which == 1 ? wk : wv);
    float4 v = *(const float4*)(s + off);
    u16x4 o = {f2bf(v.x), f2bf(v.y), f2bf(v.z), f2bf(v.w)};
    ((u16x4*)dst)[i] = o;
}

// ---------------- fused QKV GEMM: 128x128, BK=32, dbuf + 1 barrier/step ----------------
// Occupancy-first: 256 thr, 32 KiB LDS, lean epilogue (64 VGPR + 64 AGPR =
// 4 waves/SIMD). Per K-step: STAGE(next buf), 8 ds_read, lgkm fence, 16 MFMA,
// vmcnt(0)+barrier. Conflict-free slot-swizzle slot^=(row>>1)&3 (both sides).
// Q,K out [b][h][s][hd] (Q pre-scaled 0.125); V out transposed [b][h][hd][s].
__global__ __launch_bounds__(256) __attribute__((amdgpu_waves_per_eu(4)))
void k_qkv(const unsigned short* __restrict__ X,
           const unsigned short* __restrict__ W,
           const float* __restrict__ bq,
           const float* __restrict__ bk,
           const float* __restrict__ bv,
           unsigned short* __restrict__ Qo,
           unsigned short* __restrict__ Ko,
           unsigned short* __restrict__ Vt) {
    __shared__ unsigned short ldsA[2][128 * 32];  // 16 KiB dbuf
    __shared__ unsigned short ldsB[2][128 * 32];
    const int tid = threadIdx.x;
    const int lane = tid & 63, wid = tid >> 6;
    const int wm = wid >> 1, wn = wid & 1;
    const int l15 = lane & 15, g = lane >> 4;
    const int bid0 = blockIdx.x;
    const int bid = (bid0 & 7) * 192 + (bid0 >> 3);  // XCD swizzle (1536 % 8 == 0)
    const int bx = bid % 24, by = bid / 24;
    const int m0 = by * 128, n0 = bx * 128;

    // stage K-tile kt into buf d: 2 A-loads + 2 B-loads per thread
#define STAGE(d, kt)                                                        \
    {                                                                       \
        _Pragma("unroll") for (int i = 0; i < 2; ++i) {                     \
            const int e = i * 256 + tid;                                    \
            const int row = e >> 2, sl = e & 3;                             \
            const int slx = sl ^ ((row >> 1) & 3);                          \
            gload16(X + (size_t)(m0 + row) * DMODEL + (kt) * 32 + slx * 8,  \
                    (char*)&ldsA[d][0] + e * 16);                           \
            gload16(W + (size_t)(n0 + row) * DMODEL + (kt) * 32 + slx * 8,  \
                    (char*)&ldsB[d][0] + e * 16);                           \
        }                                                                   \
    }

    f32x4 acc[4][4];
#pragma unroll
    for (int i = 0; i < 4; ++i)
#pragma unroll
        for (int j = 0; j < 4; ++j) acc[i][j] = (f32x4){0.f, 0.f, 0.f, 0.f};

    STAGE(0, 0);
    asm volatile("s_waitcnt vmcnt(0)" ::: "memory");
    __builtin_amdgcn_s_barrier();

    const int ar = wm * 64 + l15;  // + mf*16
    const int br = wn * 64 + l15;  // + nf*16

#pragma unroll 2
    for (int t = 0; t < 32; ++t) {
        const char* Ac = (const char*)&ldsA[t & 1][0];
        const char* Bc = (const char*)&ldsB[t & 1][0];
        if (t < 31) STAGE((t + 1) & 1, t + 1);
        bf16x8 av[4], bvv[4];
#pragma unroll
        for (int mf = 0; mf < 4; ++mf) {
            const int row = ar + mf * 16;
            av[mf] = *(const bf16x8*)(Ac + ((row * 64 + g * 16) ^ ((((row) >> 1) & 3) << 4)));
        }
#pragma unroll
        for (int nf = 0; nf < 4; ++nf) {
            const int row = br + nf * 16;
            bvv[nf] = *(const bf16x8*)(Bc + ((row * 64 + g * 16) ^ ((((row) >> 1) & 3) << 4)));
        }
        asm volatile("s_waitcnt lgkmcnt(0)" ::: "memory");
        __builtin_amdgcn_sched_barrier(0);
        __builtin_amdgcn_s_setprio(1);
#pragma unroll
        for (int mf = 0; mf < 4; ++mf)
#pragma unroll
            for (int nf = 0; nf < 4; ++nf)
                acc[mf][nf] = MFMA16(av[mf], bvv[nf], acc[mf][nf]);
        __builtin_amdgcn_s_setprio(0);
        if (t < 31) { asm volatile("s_waitcnt vmcnt(0)" ::: "memory"); }
        __builtin_amdgcn_s_barrier();
    }
#undef STAGE

    // epilogue: unified Q/K/V scatter (V transposed), minimal live state
    const int bb = m0 >> 11;  // 128 | 2048: tiles never cross batch
    const int sbase = (m0 & 2047) + wm * 64 + g * 4;
#pragma unroll
    for (int nf = 0; nf < 4; ++nf) {
        const int col = n0 + wn * 64 + nf * 16 + l15;
        const int proj = col >> 10, rem = col & 1023;
        const int h = rem >> 6, hd = rem & 63;
        const float bias = (proj == 0 ? bq : proj == 1 ? bk : bv)[rem];
        const float scl = (proj == 0) ? 0.125f : 1.0f;
        unsigned short* dstp = (proj == 0 ? Qo : proj == 1 ? Ko : Vt) +
                               (size_t)(bb * NH + h) * (SEQ * HDIM) +
                               (proj == 2 ? (size_t)hd * SEQ : (size_t)hd);
        const int stride = (proj == 2) ? 1 : HDIM;
#pragma unroll
        for (int mf = 0; mf < 4; ++mf) {
            const int s0 = sbase + mf * 16;
#pragma unroll
            for (int r = 0; r < 4; ++r)
                dstp[(size_t)(s0 + r) * stride] = f2bf((acc[mf][nf][r] + bias) * scl);
        }
    }
}

// ---------------- sliding-window flash attention (single-pass softmax) ----------------
__global__ __launch_bounds__(256) void k_attn(const unsigned short* __restrict__ Qg,
                                              const unsigned short* __restrict__ Kg,
                                              const unsigned short* __restrict__ Vtg,
                                              const float* __restrict__ amask,
                                              float* __restrict__ out) {
    __shared__ unsigned short kl[224 * 64];      // swizzled rows (stride 128B)
    __shared__ unsigned short vl[64 * 224];      // swizzled rows (stride 448B)
    __shared__ unsigned short pl[4 * 16 * 160];  // per-wave 16x160 P tile
    const int bid0 = blockIdx.x;
    const int bid = (bid0 & 7) * 256 + (bid0 >> 3);  // XCD swizzle (2048 % 8 == 0)
    const int bh = bid >> 5, qb = bid & 31;
    const int b = bh >> 4, h = bh & 15;
    const int q0 = qb << 6;
    const int kstart = q0 - 144;
    const int tid = threadIdx.x, lane = tid & 63, w = tid >> 6;
    const int l15 = lane & 15, g = lane >> 4;

#pragma unroll
    for (int it = 0; it < 7; ++it) {
        const int c = it * 256 + tid;
        {  // K tile: row = key, 64 bf16 per row
            const int row = c >> 3, sl = c & 7;
            const int key = kstart + row;
            i32x4 v = {0, 0, 0, 0};
            if ((unsigned)key < (unsigned)SEQ)
                v = *(const i32x4*)(Kg + (size_t)(bh * SEQ + key) * HDIM + sl * 8);
            *(i32x4*)((char*)kl + ((row * 128 + sl * 16) ^ ((row & 7) << 4))) = v;
        }
        {  // Vt tile: row = hd, 224 keys per row
            const int row = c / 28, sl = c - row * 28;
            const int key0 = kstart + sl * 8;
            i32x4 v = {0, 0, 0, 0};
            if ((unsigned)key0 < (unsigned)SEQ)
                v = *(const i32x4*)(Vtg + (size_t)(bh * HDIM + row) * SEQ + key0);
            *(i32x4*)((char*)vl + ((row * 448 + sl * 16) ^ ((row & 7) << 4))) = v;
        }
    }
    const int iq = q0 + w * 16 + l15;
    const bf16x8 qf0 = *(const bf16x8*)(Qg + (size_t)(bh * SEQ + iq) * HDIM + g * 8);
    const bf16x8 qf1 = *(const bf16x8*)(Qg + (size_t)(bh * SEQ + iq) * HDIM + 32 + g * 8);
    __syncthreads();

    char* pbase = (char*)pl + w * 5120;
    const int swq = (l15 & 7) << 4;
    float s[40];

    // ---- phase 1: all QK^T chunks, masked scores into registers ----
    __builtin_amdgcn_s_setprio(1);
#pragma unroll
    for (int t = 0; t < 5; ++t) {
        const int tloc = w * 16 + t * 32;
        bf16x8 kf[2][2];
#pragma unroll
        for (int m = 0; m < 2; ++m) {
            const int row = tloc + m * 16 + l15;
            const int swz = (row & 7) << 4;
            kf[m][0] = *(const bf16x8*)((const char*)kl + ((row * 128 + g * 16) ^ swz));
            kf[m][1] = *(const bf16x8*)((const char*)kl + ((row * 128 + 64 + g * 16) ^ swz));
        }
        f32x4 sa0 = {0.f, 0.f, 0.f, 0.f}, sa1 = {0.f, 0.f, 0.f, 0.f};
        sa0 = MFMA16(kf[0][0], qf0, sa0);
        sa0 = MFMA16(kf[0][1], qf1, sa0);
        sa1 = MFMA16(kf[1][0], qf0, sa1);
        sa1 = MFMA16(kf[1][1], qf1, sa1);
#pragma unroll
        for (int f = 0; f < 2; ++f) {
            const int jb = kstart + tloc + f * 16 + g * 4;
            float4 m4 = {0.f, 0.f, 0.f, 0.f};
            if ((unsigned)jb < (unsigned)SEQ) m4 = *(const float4*)(amask + b * SEQ + jb);
            const float mvv[4] = {m4.x, m4.y, m4.z, m4.w};
#pragma unroll
            for (int r = 0; r < 4; ++r) {
                const int jg = jb + r;
                const float sc = (f == 0 ? sa0[r] : sa1[r]) + mvv[r];
                const bool ok = (jg >= 0) && (jg <= iq) && (iq - jg <= 128);
                s[t * 8 + f * 4 + r] = ok ? sc : -3.0e38f;
            }
        }
    }
    __builtin_amdgcn_s_setprio(0);

    // ---- phase 2: single softmax pass ----
    float tr[20];
#pragma unroll
    for (int i = 0; i < 20; ++i) tr[i] = fmaxf(s[i], s[i + 20]);
#pragma unroll
    for (int i = 0; i < 10; ++i) tr[i] = fmaxf(tr[i], tr[i + 10]);
#pragma unroll
    for (int i = 0; i < 5; ++i) tr[i] = fmaxf(tr[i], tr[i + 5]);
    float m = fmaxf(fmaxf(tr[0], tr[1]), fmaxf(tr[2], fmaxf(tr[3], tr[4])));
    m = fmaxf(m, __shfl_xor(m, 16));
    m = fmaxf(m, __shfl_xor(m, 32));  // always finite: key j==iq is in range

    float ls0 = 0.f, ls1 = 0.f, ls2 = 0.f, ls3 = 0.f;
#pragma unroll
    for (int i = 0; i < 40; i += 4) {
        float p0 = exp2f((s[i + 0] - m) * 1.44269504f);
        float p1 = exp2f((s[i + 1] - m) * 1.44269504f);
        float p2 = exp2f((s[i + 2] - m) * 1.44269504f);
        float p3 = exp2f((s[i + 3] - m) * 1.44269504f);
        s[i + 0] = p0; s[i + 1] = p1; s[i + 2] = p2; s[i + 3] = p3;
        ls0 += p0; ls1 += p1; ls2 += p2; ls3 += p3;
    }
    float l = (ls0 + ls1) + (ls2 + ls3);
    l += __shfl_xor(l, 16);
    l += __shfl_xor(l, 32);

    // ---- phase 3: write P (bf16) to per-wave LDS tile ----
#pragma unroll
    for (int t = 0; t < 5; ++t) {
#pragma unroll
        for (int f = 0; f < 2; ++f) {
            u16x4 pu = {f2bf(s[t * 8 + f * 4 + 0]), f2bf(s[t * 8 + f * 4 + 1]),
                        f2bf(s[t * 8 + f * 4 + 2]), f2bf(s[t * 8 + f * 4 + 3])};
            *(u16x4*)(pbase + ((l15 * 320 + t * 64 + f * 32 + g * 8) ^ swq)) = pu;
        }
    }
    asm volatile("s_waitcnt lgkmcnt(0)" ::: "memory");
    __builtin_amdgcn_sched_barrier(0);

    // ---- phase 4: PV, no rescaling ----
    f32x4 acc[4];
#pragma unroll
    for (int i = 0; i < 4; ++i) acc[i] = (f32x4){0.f, 0.f, 0.f, 0.f};
    __builtin_amdgcn_s_setprio(1);
#pragma unroll
    for (int t = 0; t < 5; ++t) {
        const int tloc = w * 16 + t * 32;
        const bf16x8 pf = *(const bf16x8*)(pbase + ((l15 * 320 + t * 64 + g * 16) ^ swq));
#pragma unroll
        for (int fn = 0; fn < 4; ++fn) {
            const int vrow = fn * 16 + l15;
            const bf16x8 vf = *(const bf16x8*)((const char*)vl +
                ((vrow * 448 + tloc * 2 + g * 16) ^ ((vrow & 7) << 4)));
            acc[fn] = MFMA16(pf, vf, acc[fn]);
        }
    }
    __builtin_amdgcn_s_setprio(0);

    float linv[4];
#pragma unroll
    for (int r = 0; r < 4; ++r) linv[r] = 1.0f / __shfl(l, g * 4 + r);
#pragma unroll
    for (int fn = 0; fn < 4; ++fn) {
#pragma unroll
        for (int r = 0; r < 4; ++r) {
            const int qrow = q0 + w * 16 + g * 4 + r;
            out[(size_t)(b * SEQ + qrow) * DMODEL + h * HDIM + fn * 16 + l15] =
                acc[fn][r] * linv[r];
        }
    }
}

extern "C" void kernel_launch(void* const* d_in, const int* in_sizes, int n_in,
                              void* d_out, int out_size, void* d_ws, size_t ws_size,
                              hipStream_t stream) {
    const float* hs = (const float*)d_in[0];
    const float* amask = (const float*)d_in[1];
    const float* wq = (const float*)d_in[2];
    const float* bq = (const float*)d_in[3];
    const float* wk = (const float*)d_in[4];
    const float* bk = (const float*)d_in[5];
    const float* wv = (const float*)d_in[6];
    const float* bv = (const float*)d_in[7];
    float* out = (float*)d_out;

    char* p = (char*)d_ws;
    unsigned short* Xbf = (unsigned short*)p;                          // 16 MB
    unsigned short* Wbf = (unsigned short*)(p + 16777216);             // 6 MB
    unsigned short* Vtb = (unsigned short*)(p + 16777216 + 6291456);   // 16 MB (not last: tail over-read safe)
    unsigned short* Qb = Vtb + 8388608;                                // 16 MB
    unsigned short* Kb = Qb + 8388608;                                 // 16 MB

    k_cvt_x<<<8192, 256, 0, stream>>>(hs, Xbf);
    k_cvt_w<<<3072, 256, 0, stream>>>(wq, wk, wv, Wbf);
    k_qkv<<<1536, 256, 0, stream>>>(Xbf, Wbf, bq, bk, bv, Qb, Kb, Vtb);
    k_attn<<<2048, 256, 0, stream>>>(Qb, Kb, Vtb, amask, out);
}

// Round 8
// 146.642 us; speedup vs baseline: 1.0436x; 1.0436x over previous
//
#include <hip/hip_runtime.h>
#include <cstdint>

#define BDIM 4
#define SEQ 2048
#define DMODEL 1024
#define NH 16
#define HDIM 64

typedef __attribute__((ext_vector_type(8))) short bf16x8;
typedef __attribute__((ext_vector_type(4))) float f32x4;
typedef __attribute__((ext_vector_type(4))) int i32x4;
typedef __attribute__((ext_vector_type(4))) unsigned short u16x4;

#define MFMA16(a, b, c) __builtin_amdgcn_mfma_f32_16x16x32_bf16(a, b, c, 0, 0, 0)

__device__ __forceinline__ unsigned short f2bf(float x) {
    unsigned int u = __float_as_uint(x);
    unsigned int r = (u + 0x7FFFu + ((u >> 16) & 1u)) >> 16;
    return (unsigned short)r;
}

__device__ __forceinline__ void gload16(const void* g, void* l) {
    __builtin_amdgcn_global_load_lds(
        (const __attribute__((address_space(1))) unsigned int*)g,
        (__attribute__((address_space(3))) unsigned int*)l, 16, 0, 0);
}

// ---------------- fused convert fp32 -> bf16 (X and Wq/Wk/Wv in one launch) ----------------
__global__ __launch_bounds__(256) void k_cvt(const float* __restrict__ hs,
                                             const float* __restrict__ wq,
                                             const float* __restrict__ wk,
                                             const float* __restrict__ wv,
                                             unsigned short* __restrict__ Xbf,
                                             unsigned short* __restrict__ Wbf) {
    int i = blockIdx.x * 256 + threadIdx.x;  // float4 index; 11264 blocks total
    if (i < 2097152) {                       // X: 8192 blocks exactly (block-uniform)
        float4 v = ((const float4*)hs)[i];
        u16x4 o = {f2bf(v.x), f2bf(v.y), f2bf(v.z), f2bf(v.w)};
        ((u16x4*)Xbf)[i] = o;
    } else {                                 // W: 3072 blocks
        int j = i - 2097152;                 // 0..786431
        int e = j << 2;
        int which = e >> 20;
        int off = e & 0xFFFFF;
        const float* s = which == 0 ? wq : (which == 1 ? wk : wv);
        float4 v = *(const float4*)(s + off);
        u16x4 o = {f2bf(v.x), f2bf(v.y), f2bf(v.z), f2bf(v.w)};
        ((u16x4*)Wbf)[j] = o;
    }
}

// ---------------- fused QKV GEMM: C = X (8192x1024) * W^T (3072x1024) ----------------
// Round-2 loop verbatim (2-barrier, compiler-scheduled; measured 73.8us/698TF —
// every explicit-fence variant regressed, m141-class) + lean unified epilogue
// (measured VGPR 64 in round 4). Q,K out [b][h][s][hd] (Q pre-scaled 0.125);
// V out transposed [b][h][hd][s].
__global__ __launch_bounds__(256) void k_qkv(const unsigned short* __restrict__ X,
                                             const unsigned short* __restrict__ W,
                                             const float* __restrict__ bq,
                                             const float* __restrict__ bk,
                                             const float* __restrict__ bv,
                                             unsigned short* __restrict__ Qo,
                                             unsigned short* __restrict__ Ko,
                                             unsigned short* __restrict__ Vt) {
    __shared__ unsigned short ldsA[128 * 32];
    __shared__ unsigned short ldsB[128 * 32];
    const int tid = threadIdx.x;
    const int lane = tid & 63, wid = tid >> 6;
    const int wm = wid >> 1, wn = wid & 1;
    const int l15 = lane & 15, g = lane >> 4;
    const int m0 = blockIdx.y * 128, n0 = blockIdx.x * 128;

    f32x4 acc[4][4];
#pragma unroll
    for (int i = 0; i < 4; ++i)
#pragma unroll
        for (int j = 0; j < 4; ++j) acc[i][j] = (f32x4){0.f, 0.f, 0.f, 0.f};

    for (int kt = 0; kt < 32; ++kt) {
        const int k0 = kt << 5;
        __syncthreads();
#pragma unroll
        for (int it = 0; it < 2; ++it) {
            const int c = it * 256 + tid;
            const int row = c >> 2, sl = c & 3;
            gload16(X + (size_t)(m0 + row) * DMODEL + k0 + sl * 8, (char*)ldsA + c * 16);
            gload16(W + (size_t)(n0 + row) * DMODEL + k0 + sl * 8, (char*)ldsB + c * 16);
        }
        __syncthreads();
        bf16x8 a[4], b[4];
#pragma unroll
        for (int f = 0; f < 4; ++f) {
            a[f] = *(const bf16x8*)((const char*)ldsA + (wm * 64 + f * 16 + l15) * 64 + g * 16);
            b[f] = *(const bf16x8*)((const char*)ldsB + (wn * 64 + f * 16 + l15) * 64 + g * 16);
        }
#pragma unroll
        for (int fm = 0; fm < 4; ++fm)
#pragma unroll
            for (int fn = 0; fn < 4; ++fn) acc[fm][fn] = MFMA16(a[fm], b[fn], acc[fm][fn]);
    }

    // epilogue: unified Q/K/V scatter (V transposed), minimal live state
    const int bb = m0 >> 11;  // 128 | 2048: tiles never cross batch
    const int sbase = (m0 & 2047) + wm * 64 + g * 4;
#pragma unroll
    for (int nf = 0; nf < 4; ++nf) {
        const int col = n0 + wn * 64 + nf * 16 + l15;
        const int proj = col >> 10, rem = col & 1023;
        const int h = rem >> 6, hd = rem & 63;
        const float bias = (proj == 0 ? bq : proj == 1 ? bk : bv)[rem];
        const float scl = (proj == 0) ? 0.125f : 1.0f;
        unsigned short* dstp = (proj == 0 ? Qo : proj == 1 ? Ko : Vt) +
                               (size_t)(bb * NH + h) * (SEQ * HDIM) +
                               (proj == 2 ? (size_t)hd * SEQ : (size_t)hd);
        const int stride = (proj == 2) ? 1 : HDIM;
#pragma unroll
        for (int mf = 0; mf < 4; ++mf) {
            const int s0 = sbase + mf * 16;
#pragma unroll
            for (int r = 0; r < 4; ++r)
                dstp[(size_t)(s0 + r) * stride] = f2bf((acc[mf][nf][r] + bias) * scl);
        }
    }
}

// ---------------- sliding-window flash attention (single-pass softmax) ----------------
__global__ __launch_bounds__(256) void k_attn(const unsigned short* __restrict__ Qg,
                                              const unsigned short* __restrict__ Kg,
                                              const unsigned short* __restrict__ Vtg,
                                              const float* __restrict__ amask,
                                              float* __restrict__ out) {
    __shared__ unsigned short kl[224 * 64];      // swizzled rows (stride 128B)
    __shared__ unsigned short vl[64 * 224];      // swizzled rows (stride 448B)
    __shared__ unsigned short pl[4 * 16 * 160];  // per-wave 16x160 P tile
    const int bid0 = blockIdx.x;
    const int bid = (bid0 & 7) * 256 + (bid0 >> 3);  // XCD swizzle (2048 % 8 == 0)
    const int bh = bid >> 5, qb = bid & 31;
    const int b = bh >> 4, h = bh & 15;
    const int q0 = qb << 6;
    const int kstart = q0 - 144;
    const int tid = threadIdx.x, lane = tid & 63, w = tid >> 6;
    const int l15 = lane & 15, g = lane >> 4;

#pragma unroll
    for (int it = 0; it < 7; ++it) {
        const int c = it * 256 + tid;
        {  // K tile: row = key, 64 bf16 per row
            const int row = c >> 3, sl = c & 7;
            const int key = kstart + row;
            i32x4 v = {0, 0, 0, 0};
            if ((unsigned)key < (unsigned)SEQ)
                v = *(const i32x4*)(Kg + (size_t)(bh * SEQ + key) * HDIM + sl * 8);
            *(i32x4*)((char*)kl + ((row * 128 + sl * 16) ^ ((row & 7) << 4))) = v;
        }
        {  // Vt tile: row = hd, 224 keys per row
            const int row = c / 28, sl = c - row * 28;
            const int key0 = kstart + sl * 8;
            i32x4 v = {0, 0, 0, 0};
            if ((unsigned)key0 < (unsigned)SEQ)
                v = *(const i32x4*)(Vtg + (size_t)(bh * HDIM + row) * SEQ + key0);
            *(i32x4*)((char*)vl + ((row * 448 + sl * 16) ^ ((row & 7) << 4))) = v;
        }
    }
    const int iq = q0 + w * 16 + l15;
    const bf16x8 qf0 = *(const bf16x8*)(Qg + (size_t)(bh * SEQ + iq) * HDIM + g * 8);
    const bf16x8 qf1 = *(const bf16x8*)(Qg + (size_t)(bh * SEQ + iq) * HDIM + 32 + g * 8);
    __syncthreads();

    char* pbase = (char*)pl + w * 5120;
    const int swq = (l15 & 7) << 4;
    float s[40];

    // ---- phase 1: all QK^T chunks, masked scores into registers ----
    __builtin_amdgcn_s_setprio(1);
#pragma unroll
    for (int t = 0; t < 5; ++t) {
        const int tloc = w * 16 + t * 32;
        bf16x8 kf[2][2];
#pragma unroll
        for (int m = 0; m < 2; ++m) {
            const int row = tloc + m * 16 + l15;
            const int swz = (row & 7) << 4;
            kf[m][0] = *(const bf16x8*)((const char*)kl + ((row * 128 + g * 16) ^ swz));
            kf[m][1] = *(const bf16x8*)((const char*)kl + ((row * 128 + 64 + g * 16) ^ swz));
        }
        f32x4 sa0 = {0.f, 0.f, 0.f, 0.f}, sa1 = {0.f, 0.f, 0.f, 0.f};
        sa0 = MFMA16(kf[0][0], qf0, sa0);
        sa0 = MFMA16(kf[0][1], qf1, sa0);
        sa1 = MFMA16(kf[1][0], qf0, sa1);
        sa1 = MFMA16(kf[1][1], qf1, sa1);
#pragma unroll
        for (int f = 0; f < 2; ++f) {
            const int jb = kstart + tloc + f * 16 + g * 4;
            float4 m4 = {0.f, 0.f, 0.f, 0.f};
            if ((unsigned)jb < (unsigned)SEQ) m4 = *(const float4*)(amask + b * SEQ + jb);
            const float mvv[4] = {m4.x, m4.y, m4.z, m4.w};
#pragma unroll
            for (int r = 0; r < 4; ++r) {
                const int jg = jb + r;
                const float sc = (f == 0 ? sa0[r] : sa1[r]) + mvv[r];
                const bool ok = (jg >= 0) && (jg <= iq) && (iq - jg <= 128);
                s[t * 8 + f * 4 + r] = ok ? sc : -3.0e38f;
            }
        }
    }
    __builtin_amdgcn_s_setprio(0);

    // ---- phase 2: single softmax pass ----
    float tr[20];
#pragma unroll
    for (int i = 0; i < 20; ++i) tr[i] = fmaxf(s[i], s[i + 20]);
#pragma unroll
    for (int i = 0; i < 10; ++i) tr[i] = fmaxf(tr[i], tr[i + 10]);
#pragma unroll
    for (int i = 0; i < 5; ++i) tr[i] = fmaxf(tr[i], tr[i + 5]);
    float m = fmaxf(fmaxf(tr[0], tr[1]), fmaxf(tr[2], fmaxf(tr[3], tr[4])));
    m = fmaxf(m, __shfl_xor(m, 16));
    m = fmaxf(m, __shfl_xor(m, 32));  // always finite: key j==iq is in range

    float ls0 = 0.f, ls1 = 0.f, ls2 = 0.f, ls3 = 0.f;
#pragma unroll
    for (int i = 0; i < 40; i += 4) {
        float p0 = exp2f((s[i + 0] - m) * 1.44269504f);
        float p1 = exp2f((s[i + 1] - m) * 1.44269504f);
        float p2 = exp2f((s[i + 2] - m) * 1.44269504f);
        float p3 = exp2f((s[i + 3] - m) * 1.44269504f);
        s[i + 0] = p0; s[i + 1] = p1; s[i + 2] = p2; s[i + 3] = p3;
        ls0 += p0; ls1 += p1; ls2 += p2; ls3 += p3;
    }
    float l = (ls0 + ls1) + (ls2 + ls3);
    l += __shfl_xor(l, 16);
    l += __shfl_xor(l, 32);

    // ---- phase 3: write P (bf16) to per-wave LDS tile ----
#pragma unroll
    for (int t = 0; t < 5; ++t) {
#pragma unroll
        for (int f = 0; f < 2; ++f) {
            u16x4 pu = {f2bf(s[t * 8 + f * 4 + 0]), f2bf(s[t * 8 + f * 4 + 1]),
                        f2bf(s[t * 8 + f * 4 + 2]), f2bf(s[t * 8 + f * 4 + 3])};
            *(u16x4*)(pbase + ((l15 * 320 + t * 64 + f * 32 + g * 8) ^ swq)) = pu;
        }
    }
    asm volatile("s_waitcnt lgkmcnt(0)" ::: "memory");
    __builtin_amdgcn_sched_barrier(0);

    // ---- phase 4: PV, no rescaling ----
    f32x4 acc[4];
#pragma unroll
    for (int i = 0; i < 4; ++i) acc[i] = (f32x4){0.f, 0.f, 0.f, 0.f};
    __builtin_amdgcn_s_setprio(1);
#pragma unroll
    for (int t = 0; t < 5; ++t) {
        const int tloc = w * 16 + t * 32;
        const bf16x8 pf = *(const bf16x8*)(pbase + ((l15 * 320 + t * 64 + g * 16) ^ swq));
#pragma unroll
        for (int fn = 0; fn < 4; ++fn) {
            const int vrow = fn * 16 + l15;
            const bf16x8 vf = *(const bf16x8*)((const char*)vl +
                ((vrow * 448 + tloc * 2 + g * 16) ^ ((vrow & 7) << 4)));
            acc[fn] = MFMA16(pf, vf, acc[fn]);
        }
    }
    __builtin_amdgcn_s_setprio(0);

    float linv[4];
#pragma unroll
    for (int r = 0; r < 4; ++r) linv[r] = 1.0f / __shfl(l, g * 4 + r);
#pragma unroll
    for (int fn = 0; fn < 4; ++fn) {
#pragma unroll
        for (int r = 0; r < 4; ++r) {
            const int qrow = q0 + w * 16 + g * 4 + r;
            out[(size_t)(b * SEQ + qrow) * DMODEL + h * HDIM + fn * 16 + l15] =
                acc[fn][r] * linv[r];
        }
    }
}

extern "C" void kernel_launch(void* const* d_in, const int* in_sizes, int n_in,
                              void* d_out, int out_size, void* d_ws, size_t ws_size,
                              hipStream_t stream) {
    const float* hs = (const float*)d_in[0];
    const float* amask = (const float*)d_in[1];
    const float* wq = (const float*)d_in[2];
    const float* bq = (const float*)d_in[3];
    const float* wk = (const float*)d_in[4];
    const float* bk = (const float*)d_in[5];
    const float* wv = (const float*)d_in[6];
    const float* bv = (const float*)d_in[7];
    float* out = (float*)d_out;

    char* p = (char*)d_ws;
    unsigned short* Xbf = (unsigned short*)p;                          // 16 MB
    unsigned short* Wbf = (unsigned short*)(p + 16777216);             // 6 MB
    unsigned short* Vtb = (unsigned short*)(p + 16777216 + 6291456);   // 16 MB (not last: tail over-read safe)
    unsigned short* Qb = Vtb + 8388608;                                // 16 MB
    unsigned short* Kb = Qb + 8388608;                                 // 16 MB

    k_cvt<<<11264, 256, 0, stream>>>(hs, wq, wk, wv, Xbf, Wbf);
    k_qkv<<<dim3(24, 64), 256, 0, stream>>>(Xbf, Wbf, bq, bk, bv, Qb, Kb, Vtb);
    k_attn<<<2048, 256, 0, stream>>>(Qb, Kb, Vtb, amask, out);
}

// Round 9
// 133.649 us; speedup vs baseline: 1.1451x; 1.0972x over previous
//
#include <hip/hip_runtime.h>
#include <cstdint>

#define BDIM 4
#define SEQ 2048
#define DMODEL 1024
#define NH 16
#define HDIM 64

typedef __attribute__((ext_vector_type(8))) short bf16x8;
typedef __attribute__((ext_vector_type(4))) float f32x4;
typedef __attribute__((ext_vector_type(4))) int i32x4;
typedef __attribute__((ext_vector_type(4))) unsigned short u16x4;

#define MFMA16(a, b, c) __builtin_amdgcn_mfma_f32_16x16x32_bf16(a, b, c, 0, 0, 0)

__device__ __forceinline__ unsigned short f2bf(float x) {
    unsigned int u = __float_as_uint(x);
    unsigned int r = (u + 0x7FFFu + ((u >> 16) & 1u)) >> 16;
    return (unsigned short)r;
}

__device__ __forceinline__ void gload16(const void* g, void* l) {
    __builtin_amdgcn_global_load_lds(
        (const __attribute__((address_space(1))) unsigned int*)g,
        (__attribute__((address_space(3))) unsigned int*)l, 16, 0, 0);
}

// ---------------- fused convert fp32 -> bf16 (X and Wq/Wk/Wv in one launch) ----------------
__global__ __launch_bounds__(256) void k_cvt(const float* __restrict__ hs,
                                             const float* __restrict__ wq,
                                             const float* __restrict__ wk,
                                             const float* __restrict__ wv,
                                             unsigned short* __restrict__ Xbf,
                                             unsigned short* __restrict__ Wbf) {
    int i = blockIdx.x * 256 + threadIdx.x;  // float4 index; 11264 blocks total
    if (i < 2097152) {                       // X: 8192 blocks exactly (block-uniform)
        float4 v = ((const float4*)hs)[i];
        u16x4 o = {f2bf(v.x), f2bf(v.y), f2bf(v.z), f2bf(v.w)};
        ((u16x4*)Xbf)[i] = o;
    } else {                                 // W: 3072 blocks
        int j = i - 2097152;                 // 0..786431
        int e = j << 2;
        int which = e >> 20;
        int off = e & 0xFFFFF;
        const float* s = which == 0 ? wq : (which == 1 ? wk : wv);
        float4 v = *(const float4*)(s + off);
        u16x4 o = {f2bf(v.x), f2bf(v.y), f2bf(v.z), f2bf(v.w)};
        ((u16x4*)Wbf)[j] = o;
    }
}

// ---------------- fused QKV GEMM: C = X (8192x1024) * W^T (3072x1024) ----------------
// Round-2 kernel VERBATIM (73.8us measured): 2-barrier compiler-scheduled loop
// + coalesced epilogue (all outputs [b][h][s][hd], hd contiguous across lanes).
// V-transposed epilogues (r3/r8) scatter 2-8B per lane across 4KB-strided lines
// -> ~64 cache-line touches per wave-store -> +13..21us. Never again.
__global__ __launch_bounds__(256) void k_qkv(const unsigned short* __restrict__ X,
                                             const unsigned short* __restrict__ W,
                                             const float* __restrict__ bq,
                                             const float* __restrict__ bk,
                                             const float* __restrict__ bv,
                                             unsigned short* __restrict__ Qo,
                                             unsigned short* __restrict__ Ko,
                                             unsigned short* __restrict__ Vo) {
    __shared__ unsigned short ldsA[128 * 32];
    __shared__ unsigned short ldsB[128 * 32];
    const int tid = threadIdx.x;
    const int lane = tid & 63, wid = tid >> 6;
    const int wm = wid >> 1, wn = wid & 1;
    const int l15 = lane & 15, g = lane >> 4;
    const int m0 = blockIdx.y * 128, n0 = blockIdx.x * 128;

    f32x4 acc[4][4];
#pragma unroll
    for (int i = 0; i < 4; ++i)
#pragma unroll
        for (int j = 0; j < 4; ++j) acc[i][j] = (f32x4){0.f, 0.f, 0.f, 0.f};

    for (int kt = 0; kt < 32; ++kt) {
        const int k0 = kt << 5;
        __syncthreads();
#pragma unroll
        for (int it = 0; it < 2; ++it) {
            const int c = it * 256 + tid;
            const int row = c >> 2, sl = c & 3;
            gload16(X + (size_t)(m0 + row) * DMODEL + k0 + sl * 8, (char*)ldsA + c * 16);
            gload16(W + (size_t)(n0 + row) * DMODEL + k0 + sl * 8, (char*)ldsB + c * 16);
        }
        __syncthreads();
        bf16x8 a[4], b[4];
#pragma unroll
        for (int f = 0; f < 4; ++f) {
            a[f] = *(const bf16x8*)((const char*)ldsA + (wm * 64 + f * 16 + l15) * 64 + g * 16);
            b[f] = *(const bf16x8*)((const char*)ldsB + (wn * 64 + f * 16 + l15) * 64 + g * 16);
        }
#pragma unroll
        for (int fm = 0; fm < 4; ++fm)
#pragma unroll
            for (int fn = 0; fn < 4; ++fn) acc[fm][fn] = MFMA16(a[fm], b[fn], acc[fm][fn]);
    }

// epilogue: scatter into Q/K/V [b][h][s][hd] bf16, bias add, Q pre-scaled by 0.125
#pragma unroll
    for (int fn = 0; fn < 4; ++fn) {
        const int col = n0 + wn * 64 + fn * 16 + l15;
        const int proj = col >> 10, rem = col & 1023;
        const int h = rem >> 6, hd = rem & 63;
        const float* bp = proj == 0 ? bq : (proj == 1 ? bk : bv);
        const float bias = bp[rem];
        const float scl = (proj == 0) ? 0.125f : 1.0f;
        unsigned short* dst = proj == 0 ? Qo : (proj == 1 ? Ko : Vo);
#pragma unroll
        for (int fm = 0; fm < 4; ++fm) {
#pragma unroll
            for (int r = 0; r < 4; ++r) {
                const int m = m0 + wm * 64 + fm * 16 + g * 4 + r;
                const int bb = m >> 11, s = m & 2047;
                dst[(size_t)((bb * NH + h) * SEQ + s) * HDIM + hd] =
                    f2bf((acc[fm][fn][r] + bias) * scl);
            }
        }
    }
}

// ---------------- sliding-window flash attention (single-pass softmax) ----------------
// block = (b,h, 64 queries); 4 waves x 16 queries; keys staged [q0-144, q0+79].
// V consumed directly from [b][h][s][hd]: staged with coalesced 16B reads +
// in-LDS transpose (8 rotated ds_write_b16 into the swizzled vl[hd][key] tile).
__global__ __launch_bounds__(256) void k_attn(const unsigned short* __restrict__ Qg,
                                              const unsigned short* __restrict__ Kg,
                                              const unsigned short* __restrict__ Vg,
                                              const float* __restrict__ amask,
                                              float* __restrict__ out) {
    __shared__ unsigned short kl[224 * 64];      // swizzled rows (stride 128B)
    __shared__ unsigned short vl[64 * 224];      // swizzled rows (stride 448B)
    __shared__ unsigned short pl[4 * 16 * 160];  // per-wave 16x160 P tile
    const int bid0 = blockIdx.x;
    const int bid = (bid0 & 7) * 256 + (bid0 >> 3);  // XCD swizzle (2048 % 8 == 0)
    const int bh = bid >> 5, qb = bid & 31;
    const int b = bh >> 4, h = bh & 15;
    const int q0 = qb << 6;
    const int kstart = q0 - 144;
    const int tid = threadIdx.x, lane = tid & 63, w = tid >> 6;
    const int l15 = lane & 15, g = lane >> 4;

#pragma unroll
    for (int it = 0; it < 7; ++it) {
        const int c = it * 256 + tid;
        const int row = c >> 3, sl = c & 7;  // row = key index 0..223, sl = 16B slot
        const int key = kstart + row;
        {  // K tile: row-major [key][hd], b128 write
            i32x4 v = {0, 0, 0, 0};
            if ((unsigned)key < (unsigned)SEQ)
                v = *(const i32x4*)(Kg + (size_t)(bh * SEQ + key) * HDIM + sl * 8);
            *(i32x4*)((char*)kl + ((row * 128 + sl * 16) ^ ((row & 7) << 4))) = v;
        }
        {  // V tile: read [key][hd] coalesced, transpose into vl[hd][key]
            i32x4 v = {0, 0, 0, 0};
            if ((unsigned)key < (unsigned)SEQ)
                v = *(const i32x4*)(Vg + (size_t)(bh * SEQ + key) * HDIM + sl * 8);
            union { i32x4 v; unsigned short u[8]; } uu;
            uu.v = v;
#pragma unroll
            for (int j = 0; j < 8; ++j) {
                const int jj = (j + row) & 7;        // rotate to spread LDS banks
                const int hd = sl * 8 + jj;
                *(unsigned short*)((char*)vl +
                    ((hd * 448 + row * 2) ^ ((hd & 7) << 4))) = uu.u[jj];
            }
        }
    }
    const int iq = q0 + w * 16 + l15;
    const bf16x8 qf0 = *(const bf16x8*)(Qg + (size_t)(bh * SEQ + iq) * HDIM + g * 8);
    const bf16x8 qf1 = *(const bf16x8*)(Qg + (size_t)(bh * SEQ + iq) * HDIM + 32 + g * 8);
    __syncthreads();

    char* pbase = (char*)pl + w * 5120;
    const int swq = (l15 & 7) << 4;
    float s[40];

    // ---- phase 1: all QK^T chunks, masked scores into registers ----
    __builtin_amdgcn_s_setprio(1);
#pragma unroll
    for (int t = 0; t < 5; ++t) {
        const int tloc = w * 16 + t * 32;
        bf16x8 kf[2][2];
#pragma unroll
        for (int m = 0; m < 2; ++m) {
            const int row = tloc + m * 16 + l15;
            const int swz = (row & 7) << 4;
            kf[m][0] = *(const bf16x8*)((const char*)kl + ((row * 128 + g * 16) ^ swz));
            kf[m][1] = *(const bf16x8*)((const char*)kl + ((row * 128 + 64 + g * 16) ^ swz));
        }
        f32x4 sa0 = {0.f, 0.f, 0.f, 0.f}, sa1 = {0.f, 0.f, 0.f, 0.f};
        sa0 = MFMA16(kf[0][0], qf0, sa0);
        sa0 = MFMA16(kf[0][1], qf1, sa0);
        sa1 = MFMA16(kf[1][0], qf0, sa1);
        sa1 = MFMA16(kf[1][1], qf1, sa1);
#pragma unroll
        for (int f = 0; f < 2; ++f) {
            const int jb = kstart + tloc + f * 16 + g * 4;
            float4 m4 = {0.f, 0.f, 0.f, 0.f};
            if ((unsigned)jb < (unsigned)SEQ) m4 = *(const float4*)(amask + b * SEQ + jb);
            const float mvv[4] = {m4.x, m4.y, m4.z, m4.w};
#pragma unroll
            for (int r = 0; r < 4; ++r) {
                const int jg = jb + r;
                const float sc = (f == 0 ? sa0[r] : sa1[r]) + mvv[r];
                const bool ok = (jg >= 0) && (jg <= iq) && (iq - jg <= 128);
                s[t * 8 + f * 4 + r] = ok ? sc : -3.0e38f;
            }
        }
    }
    __builtin_amdgcn_s_setprio(0);

    // ---- phase 2: single softmax pass ----
    float tr[20];
#pragma unroll
    for (int i = 0; i < 20; ++i) tr[i] = fmaxf(s[i], s[i + 20]);
#pragma unroll
    for (int i = 0; i < 10; ++i) tr[i] = fmaxf(tr[i], tr[i + 10]);
#pragma unroll
    for (int i = 0; i < 5; ++i) tr[i] = fmaxf(tr[i], tr[i + 5]);
    float m = fmaxf(fmaxf(tr[0], tr[1]), fmaxf(tr[2], fmaxf(tr[3], tr[4])));
    m = fmaxf(m, __shfl_xor(m, 16));
    m = fmaxf(m, __shfl_xor(m, 32));  // always finite: key j==iq is in range

    float ls0 = 0.f, ls1 = 0.f, ls2 = 0.f, ls3 = 0.f;
#pragma unroll
    for (int i = 0; i < 40; i += 4) {
        float p0 = exp2f((s[i + 0] - m) * 1.44269504f);
        float p1 = exp2f((s[i + 1] - m) * 1.44269504f);
        float p2 = exp2f((s[i + 2] - m) * 1.44269504f);
        float p3 = exp2f((s[i + 3] - m) * 1.44269504f);
        s[i + 0] = p0; s[i + 1] = p1; s[i + 2] = p2; s[i + 3] = p3;
        ls0 += p0; ls1 += p1; ls2 += p2; ls3 += p3;
    }
    float l = (ls0 + ls1) + (ls2 + ls3);
    l += __shfl_xor(l, 16);
    l += __shfl_xor(l, 32);

    // ---- phase 3: write P (bf16) to per-wave LDS tile ----
#pragma unroll
    for (int t = 0; t < 5; ++t) {
#pragma unroll
        for (int f = 0; f < 2; ++f) {
            u16x4 pu = {f2bf(s[t * 8 + f * 4 + 0]), f2bf(s[t * 8 + f * 4 + 1]),
                        f2bf(s[t * 8 + f * 4 + 2]), f2bf(s[t * 8 + f * 4 + 3])};
            *(u16x4*)(pbase + ((l15 * 320 + t * 64 + f * 32 + g * 8) ^ swq)) = pu;
        }
    }
    asm volatile("s_waitcnt lgkmcnt(0)" ::: "memory");
    __builtin_amdgcn_sched_barrier(0);

    // ---- phase 4: PV, no rescaling ----
    f32x4 acc[4];
#pragma unroll
    for (int i = 0; i < 4; ++i) acc[i] = (f32x4){0.f, 0.f, 0.f, 0.f};
    __builtin_amdgcn_s_setprio(1);
#pragma unroll
    for (int t = 0; t < 5; ++t) {
        const int tloc = w * 16 + t * 32;
        const bf16x8 pf = *(const bf16x8*)(pbase + ((l15 * 320 + t * 64 + g * 16) ^ swq));
#pragma unroll
        for (int fn = 0; fn < 4; ++fn) {
            const int vrow = fn * 16 + l15;
            const bf16x8 vf = *(const bf16x8*)((const char*)vl +
                ((vrow * 448 + tloc * 2 + g * 16) ^ ((vrow & 7) << 4)));
            acc[fn] = MFMA16(pf, vf, acc[fn]);
        }
    }
    __builtin_amdgcn_s_setprio(0);

    float linv[4];
#pragma unroll
    for (int r = 0; r < 4; ++r) linv[r] = 1.0f / __shfl(l, g * 4 + r);
#pragma unroll
    for (int fn = 0; fn < 4; ++fn) {
#pragma unroll
        for (int r = 0; r < 4; ++r) {
            const int qrow = q0 + w * 16 + g * 4 + r;
            out[(size_t)(b * SEQ + qrow) * DMODEL + h * HDIM + fn * 16 + l15] =
                acc[fn][r] * linv[r];
        }
    }
}

extern "C" void kernel_launch(void* const* d_in, const int* in_sizes, int n_in,
                              void* d_out, int out_size, void* d_ws, size_t ws_size,
                              hipStream_t stream) {
    const float* hs = (const float*)d_in[0];
    const float* amask = (const float*)d_in[1];
    const float* wq = (const float*)d_in[2];
    const float* bq = (const float*)d_in[3];
    const float* wk = (const float*)d_in[4];
    const float* bk = (const float*)d_in[5];
    const float* wv = (const float*)d_in[6];
    const float* bv = (const float*)d_in[7];
    float* out = (float*)d_out;

    char* p = (char*)d_ws;
    unsigned short* Xbf = (unsigned short*)p;                          // 16 MB
    unsigned short* Wbf = (unsigned short*)(p + 16777216);             // 6 MB
    unsigned short* Qb = (unsigned short*)(p + 16777216 + 6291456);    // 16 MB
    unsigned short* Kb = Qb + 8388608;                                 // 16 MB
    unsigned short* Vb = Kb + 8388608;                                 // 16 MB

    k_cvt<<<11264, 256, 0, stream>>>(hs, wq, wk, wv, Xbf, Wbf);
    k_qkv<<<dim3(24, 64), 256, 0, stream>>>(Xbf, Wbf, bq, bk, bv, Qb, Kb, Vb);
    k_attn<<<2048, 256, 0, stream>>>(Qb, Kb, Vb, amask, out);
}

// Round 10
// 129.710 us; speedup vs baseline: 1.1799x; 1.0304x over previous
//
#include <hip/hip_runtime.h>
#include <cstdint>

#define BDIM 4
#define SEQ 2048
#define DMODEL 1024
#define NH 16
#define HDIM 64

typedef __attribute__((ext_vector_type(8))) short bf16x8;
typedef __attribute__((ext_vector_type(4))) float f32x4;
typedef __attribute__((ext_vector_type(4))) int i32x4;
typedef __attribute__((ext_vector_type(4))) unsigned short u16x4;

#define MFMA16(a, b, c) __builtin_amdgcn_mfma_f32_16x16x32_bf16(a, b, c, 0, 0, 0)

__device__ __forceinline__ unsigned short f2bf(float x) {
    unsigned int u = __float_as_uint(x);
    unsigned int r = (u + 0x7FFFu + ((u >> 16) & 1u)) >> 16;
    return (unsigned short)r;
}

__device__ __forceinline__ void gload16(const void* g, void* l) {
    __builtin_amdgcn_global_load_lds(
        (const __attribute__((address_space(1))) unsigned int*)g,
        (__attribute__((address_space(3))) unsigned int*)l, 16, 0, 0);
}

// ---------------- fused convert fp32 -> bf16 (X and Wq/Wk/Wv in one launch) ----------------
__global__ __launch_bounds__(256) void k_cvt(const float* __restrict__ hs,
                                             const float* __restrict__ wq,
                                             const float* __restrict__ wk,
                                             const float* __restrict__ wv,
                                             unsigned short* __restrict__ Xbf,
                                             unsigned short* __restrict__ Wbf) {
    int i = blockIdx.x * 256 + threadIdx.x;  // float4 index; 11264 blocks total
    if (i < 2097152) {                       // X: 8192 blocks exactly (block-uniform)
        float4 v = ((const float4*)hs)[i];
        u16x4 o = {f2bf(v.x), f2bf(v.y), f2bf(v.z), f2bf(v.w)};
        ((u16x4*)Xbf)[i] = o;
    } else {                                 // W: 3072 blocks
        int j = i - 2097152;                 // 0..786431
        int e = j << 2;
        int which = e >> 20;
        int off = e & 0xFFFFF;
        const float* s = which == 0 ? wq : (which == 1 ? wk : wv);
        float4 v = *(const float4*)(s + off);
        u16x4 o = {f2bf(v.x), f2bf(v.y), f2bf(v.z), f2bf(v.w)};
        ((u16x4*)Wbf)[j] = o;
    }
}

// ---------------- fused QKV GEMM: C = X (8192x1024) * W^T (3072x1024) ----------------
// Measured-optimal structure (73.5us / ~700TF): 2-barrier compiler-scheduled
// loop, NO asm fences in-loop (m141-class regressions), coalesced epilogue
// (all outputs [b][h][s][hd], hd contiguous across lanes; V-transposed stores
// scatter 4KB-strided -> +13..21us, measured r3/r8).
__global__ __launch_bounds__(256) void k_qkv(const unsigned short* __restrict__ X,
                                             const unsigned short* __restrict__ W,
                                             const float* __restrict__ bq,
                                             const float* __restrict__ bk,
                                             const float* __restrict__ bv,
                                             unsigned short* __restrict__ Qo,
                                             unsigned short* __restrict__ Ko,
                                             unsigned short* __restrict__ Vo) {
    __shared__ unsigned short ldsA[128 * 32];
    __shared__ unsigned short ldsB[128 * 32];
    const int tid = threadIdx.x;
    const int lane = tid & 63, wid = tid >> 6;
    const int wm = wid >> 1, wn = wid & 1;
    const int l15 = lane & 15, g = lane >> 4;
    const int m0 = blockIdx.y * 128, n0 = blockIdx.x * 128;

    f32x4 acc[4][4];
#pragma unroll
    for (int i = 0; i < 4; ++i)
#pragma unroll
        for (int j = 0; j < 4; ++j) acc[i][j] = (f32x4){0.f, 0.f, 0.f, 0.f};

    for (int kt = 0; kt < 32; ++kt) {
        const int k0 = kt << 5;
        __syncthreads();
#pragma unroll
        for (int it = 0; it < 2; ++it) {
            const int c = it * 256 + tid;
            const int row = c >> 2, sl = c & 3;
            gload16(X + (size_t)(m0 + row) * DMODEL + k0 + sl * 8, (char*)ldsA + c * 16);
            gload16(W + (size_t)(n0 + row) * DMODEL + k0 + sl * 8, (char*)ldsB + c * 16);
        }
        __syncthreads();
        bf16x8 a[4], b[4];
#pragma unroll
        for (int f = 0; f < 4; ++f) {
            a[f] = *(const bf16x8*)((const char*)ldsA + (wm * 64 + f * 16 + l15) * 64 + g * 16);
            b[f] = *(const bf16x8*)((const char*)ldsB + (wn * 64 + f * 16 + l15) * 64 + g * 16);
        }
#pragma unroll
        for (int fm = 0; fm < 4; ++fm)
#pragma unroll
            for (int fn = 0; fn < 4; ++fn) acc[fm][fn] = MFMA16(a[fm], b[fn], acc[fm][fn]);
    }

// epilogue: scatter into Q/K/V [b][h][s][hd] bf16, bias add, Q pre-scaled by 0.125
#pragma unroll
    for (int fn = 0; fn < 4; ++fn) {
        const int col = n0 + wn * 64 + fn * 16 + l15;
        const int proj = col >> 10, rem = col & 1023;
        const int h = rem >> 6, hd = rem & 63;
        const float* bp = proj == 0 ? bq : (proj == 1 ? bk : bv);
        const float bias = bp[rem];
        const float scl = (proj == 0) ? 0.125f : 1.0f;
        unsigned short* dst = proj == 0 ? Qo : (proj == 1 ? Ko : Vo);
#pragma unroll
        for (int fm = 0; fm < 4; ++fm) {
#pragma unroll
            for (int r = 0; r < 4; ++r) {
                const int m = m0 + wm * 64 + fm * 16 + g * 4 + r;
                const int bb = m >> 11, s = m & 2047;
                dst[(size_t)((bb * NH + h) * SEQ + s) * HDIM + hd] =
                    f2bf((acc[fm][fn][r] + bias) * scl);
            }
        }
    }
}

// ---------------- V transpose: [b][h][s][hd] -> [b][h][hd][s] ----------------
// 64x64 tile; 512 threads x 8 elems each side; row stride 80 u16 (16B-aligned).
// Measured ~7us in round 2.
__global__ __launch_bounds__(256) void k_trv(const unsigned short* __restrict__ V,
                                             unsigned short* __restrict__ Vt) {
    __shared__ unsigned short tl[64][80];
    const int bh = blockIdx.y, s0 = blockIdx.x * 64;
    const int tid = threadIdx.x;
#pragma unroll
    for (int it = 0; it < 2; ++it) {
        const int c = it * 256 + tid;        // 0..511
        const int sl = c >> 3, hs = c & 7;   // sl: s-row 0..63, hs: 8-elem hd slot
        i32x4 v = *(const i32x4*)(V + (size_t)(bh * SEQ + s0 + sl) * HDIM + hs * 8);
        union { i32x4 v; unsigned short u[8]; } uu;
        uu.v = v;
#pragma unroll
        for (int j = 0; j < 8; ++j) tl[hs * 8 + j][sl] = uu.u[j];
    }
    __syncthreads();
#pragma unroll
    for (int it = 0; it < 2; ++it) {
        const int c = it * 256 + tid;
        const int hd = c >> 3, ss = c & 7;   // hd 0..63, ss: 8-elem s slot
        i32x4 o = *(const i32x4*)(&tl[hd][ss * 8]);
        *(i32x4*)(Vt + (size_t)(bh * HDIM + hd) * SEQ + s0 + ss * 8) = o;
    }
}

// ---------------- sliding-window flash attention (single-pass softmax) ----------------
// block = (b,h, 64 queries); 4 waves x 16 queries; keys staged [q0-144, q0+79].
// Round-3 version verbatim (~32us): Vt staged from global with b128 ops.
__global__ __launch_bounds__(256) void k_attn(const unsigned short* __restrict__ Qg,
                                              const unsigned short* __restrict__ Kg,
                                              const unsigned short* __restrict__ Vtg,
                                              const float* __restrict__ amask,
                                              float* __restrict__ out) {
    __shared__ unsigned short kl[224 * 64];      // swizzled rows (stride 128B)
    __shared__ unsigned short vl[64 * 224];      // swizzled rows (stride 448B)
    __shared__ unsigned short pl[4 * 16 * 160];  // per-wave 16x160 P tile
    const int bid0 = blockIdx.x;
    const int bid = (bid0 & 7) * 256 + (bid0 >> 3);  // XCD swizzle (2048 % 8 == 0)
    const int bh = bid >> 5, qb = bid & 31;
    const int b = bh >> 4, h = bh & 15;
    const int q0 = qb << 6;
    const int kstart = q0 - 144;
    const int tid = threadIdx.x, lane = tid & 63, w = tid >> 6;
    const int l15 = lane & 15, g = lane >> 4;

#pragma unroll
    for (int it = 0; it < 7; ++it) {
        const int c = it * 256 + tid;
        {  // K tile: row = key, 64 bf16 per row
            const int row = c >> 3, sl = c & 7;
            const int key = kstart + row;
            i32x4 v = {0, 0, 0, 0};
            if ((unsigned)key < (unsigned)SEQ)
                v = *(const i32x4*)(Kg + (size_t)(bh * SEQ + key) * HDIM + sl * 8);
            *(i32x4*)((char*)kl + ((row * 128 + sl * 16) ^ ((row & 7) << 4))) = v;
        }
        {  // Vt tile: row = hd, 224 keys per row
            const int row = c / 28, sl = c - row * 28;
            const int key0 = kstart + sl * 8;
            i32x4 v = {0, 0, 0, 0};
            if ((unsigned)key0 < (unsigned)SEQ)
                v = *(const i32x4*)(Vtg + (size_t)(bh * HDIM + row) * SEQ + key0);
            *(i32x4*)((char*)vl + ((row * 448 + sl * 16) ^ ((row & 7) << 4))) = v;
        }
    }
    const int iq = q0 + w * 16 + l15;
    const bf16x8 qf0 = *(const bf16x8*)(Qg + (size_t)(bh * SEQ + iq) * HDIM + g * 8);
    const bf16x8 qf1 = *(const bf16x8*)(Qg + (size_t)(bh * SEQ + iq) * HDIM + 32 + g * 8);
    __syncthreads();

    char* pbase = (char*)pl + w * 5120;
    const int swq = (l15 & 7) << 4;
    float s[40];

    // ---- phase 1: all QK^T chunks, masked scores into registers ----
    __builtin_amdgcn_s_setprio(1);
#pragma unroll
    for (int t = 0; t < 5; ++t) {
        const int tloc = w * 16 + t * 32;
        bf16x8 kf[2][2];
#pragma unroll
        for (int m = 0; m < 2; ++m) {
            const int row = tloc + m * 16 + l15;
            const int swz = (row & 7) << 4;
            kf[m][0] = *(const bf16x8*)((const char*)kl + ((row * 128 + g * 16) ^ swz));
            kf[m][1] = *(const bf16x8*)((const char*)kl + ((row * 128 + 64 + g * 16) ^ swz));
        }
        f32x4 sa0 = {0.f, 0.f, 0.f, 0.f}, sa1 = {0.f, 0.f, 0.f, 0.f};
        sa0 = MFMA16(kf[0][0], qf0, sa0);
        sa0 = MFMA16(kf[0][1], qf1, sa0);
        sa1 = MFMA16(kf[1][0], qf0, sa1);
        sa1 = MFMA16(kf[1][1], qf1, sa1);
#pragma unroll
        for (int f = 0; f < 2; ++f) {
            const int jb = kstart + tloc + f * 16 + g * 4;
            float4 m4 = {0.f, 0.f, 0.f, 0.f};
            if ((unsigned)jb < (unsigned)SEQ) m4 = *(const float4*)(amask + b * SEQ + jb);
            const float mvv[4] = {m4.x, m4.y, m4.z, m4.w};
#pragma unroll
            for (int r = 0; r < 4; ++r) {
                const int jg = jb + r;
                const float sc = (f == 0 ? sa0[r] : sa1[r]) + mvv[r];
                const bool ok = (jg >= 0) && (jg <= iq) && (iq - jg <= 128);
                s[t * 8 + f * 4 + r] = ok ? sc : -3.0e38f;
            }
        }
    }
    __builtin_amdgcn_s_setprio(0);

    // ---- phase 2: single softmax pass ----
    float tr[20];
#pragma unroll
    for (int i = 0; i < 20; ++i) tr[i] = fmaxf(s[i], s[i + 20]);
#pragma unroll
    for (int i = 0; i < 10; ++i) tr[i] = fmaxf(tr[i], tr[i + 10]);
#pragma unroll
    for (int i = 0; i < 5; ++i) tr[i] = fmaxf(tr[i], tr[i + 5]);
    float m = fmaxf(fmaxf(tr[0], tr[1]), fmaxf(tr[2], fmaxf(tr[3], tr[4])));
    m = fmaxf(m, __shfl_xor(m, 16));
    m = fmaxf(m, __shfl_xor(m, 32));  // always finite: key j==iq is in range

    float ls0 = 0.f, ls1 = 0.f, ls2 = 0.f, ls3 = 0.f;
#pragma unroll
    for (int i = 0; i < 40; i += 4) {
        float p0 = exp2f((s[i + 0] - m) * 1.44269504f);
        float p1 = exp2f((s[i + 1] - m) * 1.44269504f);
        float p2 = exp2f((s[i + 2] - m) * 1.44269504f);
        float p3 = exp2f((s[i + 3] - m) * 1.44269504f);
        s[i + 0] = p0; s[i + 1] = p1; s[i + 2] = p2; s[i + 3] = p3;
        ls0 += p0; ls1 += p1; ls2 += p2; ls3 += p3;
    }
    float l = (ls0 + ls1) + (ls2 + ls3);
    l += __shfl_xor(l, 16);
    l += __shfl_xor(l, 32);

    // ---- phase 3: write P (bf16) to per-wave LDS tile ----
#pragma unroll
    for (int t = 0; t < 5; ++t) {
#pragma unroll
        for (int f = 0; f < 2; ++f) {
            u16x4 pu = {f2bf(s[t * 8 + f * 4 + 0]), f2bf(s[t * 8 + f * 4 + 1]),
                        f2bf(s[t * 8 + f * 4 + 2]), f2bf(s[t * 8 + f * 4 + 3])};
            *(u16x4*)(pbase + ((l15 * 320 + t * 64 + f * 32 + g * 8) ^ swq)) = pu;
        }
    }
    asm volatile("s_waitcnt lgkmcnt(0)" ::: "memory");
    __builtin_amdgcn_sched_barrier(0);

    // ---- phase 4: PV, no rescaling ----
    f32x4 acc[4];
#pragma unroll
    for (int i = 0; i < 4; ++i) acc[i] = (f32x4){0.f, 0.f, 0.f, 0.f};
    __builtin_amdgcn_s_setprio(1);
#pragma unroll
    for (int t = 0; t < 5; ++t) {
        const int tloc = w * 16 + t * 32;
        const bf16x8 pf = *(const bf16x8*)(pbase + ((l15 * 320 + t * 64 + g * 16) ^ swq));
#pragma unroll
        for (int fn = 0; fn < 4; ++fn) {
            const int vrow = fn * 16 + l15;
            const bf16x8 vf = *(const bf16x8*)((const char*)vl +
                ((vrow * 448 + tloc * 2 + g * 16) ^ ((vrow & 7) << 4)));
            acc[fn] = MFMA16(pf, vf, acc[fn]);
        }
    }
    __builtin_amdgcn_s_setprio(0);

    float linv[4];
#pragma unroll
    for (int r = 0; r < 4; ++r) linv[r] = 1.0f / __shfl(l, g * 4 + r);
#pragma unroll
    for (int fn = 0; fn < 4; ++fn) {
#pragma unroll
        for (int r = 0; r < 4; ++r) {
            const int qrow = q0 + w * 16 + g * 4 + r;
            out[(size_t)(b * SEQ + qrow) * DMODEL + h * HDIM + fn * 16 + l15] =
                acc[fn][r] * linv[r];
        }
    }
}

extern "C" void kernel_launch(void* const* d_in, const int* in_sizes, int n_in,
                              void* d_out, int out_size, void* d_ws, size_t ws_size,
                              hipStream_t stream) {
    const float* hs = (const float*)d_in[0];
    const float* amask = (const float*)d_in[1];
    const float* wq = (const float*)d_in[2];
    const float* bq = (const float*)d_in[3];
    const float* wk = (const float*)d_in[4];
    const float* bk = (const float*)d_in[5];
    const float* wv = (const float*)d_in[6];
    const float* bv = (const float*)d_in[7];
    float* out = (float*)d_out;

    char* p = (char*)d_ws;
    unsigned short* Xbf = (unsigned short*)p;                          // 16 MB
    unsigned short* Wbf = (unsigned short*)(p + 16777216);             // 6 MB
    unsigned short* Qb = (unsigned short*)(p + 16777216 + 6291456);    // 16 MB
    unsigned short* Kb = Qb + 8388608;                                 // 16 MB
    unsigned short* Vb = Kb + 8388608;                                 // 16 MB
    unsigned short* Vtb = Xbf;  // alias: X fully consumed by GEMM before k_trv

    k_cvt<<<11264, 256, 0, stream>>>(hs, wq, wk, wv, Xbf, Wbf);
    k_qkv<<<dim3(24, 64), 256, 0, stream>>>(Xbf, Wbf, bq, bk, bv, Qb, Kb, Vb);
    k_trv<<<dim3(32, 64), 256, 0, stream>>>(Vb, Vtb);
    k_attn<<<2048, 256, 0, stream>>>(Qb, Kb, Vtb, amask, out);
}

// Round 11
// 129.626 us; speedup vs baseline: 1.1806x; 1.0007x over previous
//
#include <hip/hip_runtime.h>
#include <cstdint>

#define BDIM 4
#define SEQ 2048
#define DMODEL 1024
#define NH 16
#define HDIM 64

typedef __attribute__((ext_vector_type(8))) short bf16x8;
typedef __attribute__((ext_vector_type(4))) float f32x4;
typedef __attribute__((ext_vector_type(4))) int i32x4;
typedef __attribute__((ext_vector_type(4))) unsigned short u16x4;

#define MFMA16(a, b, c) __builtin_amdgcn_mfma_f32_16x16x32_bf16(a, b, c, 0, 0, 0)

__device__ __forceinline__ unsigned short f2bf(float x) {
    unsigned int u = __float_as_uint(x);
    unsigned int r = (u + 0x7FFFu + ((u >> 16) & 1u)) >> 16;
    return (unsigned short)r;
}

__device__ __forceinline__ void gload16(const void* g, void* l) {
    __builtin_amdgcn_global_load_lds(
        (const __attribute__((address_space(1))) unsigned int*)g,
        (__attribute__((address_space(3))) unsigned int*)l, 16, 0, 0);
}

// ---------------- fused convert fp32 -> bf16 (X and Wq/Wk/Wv in one launch) ----------------
__global__ __launch_bounds__(256) void k_cvt(const float* __restrict__ hs,
                                             const float* __restrict__ wq,
                                             const float* __restrict__ wk,
                                             const float* __restrict__ wv,
                                             unsigned short* __restrict__ Xbf,
                                             unsigned short* __restrict__ Wbf) {
    int i = blockIdx.x * 256 + threadIdx.x;  // float4 index; 11264 blocks total
    if (i < 2097152) {                       // X: 8192 blocks exactly (block-uniform)
        float4 v = ((const float4*)hs)[i];
        u16x4 o = {f2bf(v.x), f2bf(v.y), f2bf(v.z), f2bf(v.w)};
        ((u16x4*)Xbf)[i] = o;
    } else {                                 // W: 3072 blocks
        int j = i - 2097152;                 // 0..786431
        int e = j << 2;
        int which = e >> 20;
        int off = e & 0xFFFFF;
        const float* s = which == 0 ? wq : (which == 1 ? wk : wv);
        float4 v = *(const float4*)(s + off);
        u16x4 o = {f2bf(v.x), f2bf(v.y), f2bf(v.z), f2bf(v.w)};
        ((u16x4*)Wbf)[j] = o;
    }
}

// ---------------- fused QKV GEMM: C = X (8192x1024) * W^T (3072x1024) ----------------
// Measured-optimal loop (73.5us): 2-barrier compiler-scheduled, NO in-loop asm
// fences (m141-class regressions). Q/K epilogue coalesced [b][h][s][hd]
// (Q pre-scaled 0.125). V blocks (bx 16-23, block-uniform) transpose via LDS
// bounce and store Vt [b][h][hd][s] in 256-B runs (kills the k_trv pass;
// direct per-lane Vt stores scatter 64 lines/inst -> +13..21us, r3/r8).
__global__ __launch_bounds__(256) void k_qkv(const unsigned short* __restrict__ X,
                                             const unsigned short* __restrict__ W,
                                             const float* __restrict__ bq,
                                             const float* __restrict__ bk,
                                             const float* __restrict__ bv,
                                             unsigned short* __restrict__ Qo,
                                             unsigned short* __restrict__ Ko,
                                             unsigned short* __restrict__ Vt) {
    __shared__ unsigned short smem[8320];     // A:4096 u16 | B:4096 u16 ; T:[128][65]
    unsigned short* ldsA = smem;
    unsigned short* ldsB = smem + 4096;
    const int tid = threadIdx.x;
    const int lane = tid & 63, wid = tid >> 6;
    const int wm = wid >> 1, wn = wid & 1;
    const int l15 = lane & 15, g = lane >> 4;
    const int m0 = blockIdx.y * 128, n0 = blockIdx.x * 128;

    f32x4 acc[4][4];
#pragma unroll
    for (int i = 0; i < 4; ++i)
#pragma unroll
        for (int j = 0; j < 4; ++j) acc[i][j] = (f32x4){0.f, 0.f, 0.f, 0.f};

    for (int kt = 0; kt < 32; ++kt) {
        const int k0 = kt << 5;
        __syncthreads();
#pragma unroll
        for (int it = 0; it < 2; ++it) {
            const int c = it * 256 + tid;
            const int row = c >> 2, sl = c & 3;
            gload16(X + (size_t)(m0 + row) * DMODEL + k0 + sl * 8, (char*)ldsA + c * 16);
            gload16(W + (size_t)(n0 + row) * DMODEL + k0 + sl * 8, (char*)ldsB + c * 16);
        }
        __syncthreads();
        bf16x8 a[4], b[4];
#pragma unroll
        for (int f = 0; f < 4; ++f) {
            a[f] = *(const bf16x8*)((const char*)ldsA + (wm * 64 + f * 16 + l15) * 64 + g * 16);
            b[f] = *(const bf16x8*)((const char*)ldsB + (wn * 64 + f * 16 + l15) * 64 + g * 16);
        }
#pragma unroll
        for (int fm = 0; fm < 4; ++fm)
#pragma unroll
            for (int fn = 0; fn < 4; ++fn) acc[fm][fn] = MFMA16(a[fm], b[fn], acc[fm][fn]);
    }

    if ((n0 >> 10) == 2) {
        // ---- V block: LDS-bounce transpose, coalesced Vt store ----
        unsigned short* ldsT = smem;          // [128][65] u16
        const int bb = m0 >> 11, sblock = m0 & 2047;
        const int hbase = (n0 & 1023) >> 6;   // 2 heads per block
#pragma unroll
        for (int p = 0; p < 2; ++p) {
            __syncthreads();                  // LDS free (A/B reads or pass p-1 done)
            if (wn == p) {
#pragma unroll
                for (int fn = 0; fn < 4; ++fn) {
                    const float bias = bv[(n0 & 1023) + p * 64 + fn * 16 + l15];
#pragma unroll
                    for (int fm = 0; fm < 4; ++fm)
#pragma unroll
                        for (int r = 0; r < 4; ++r)
                            ldsT[(wm * 64 + fm * 16 + g * 4 + r) * 65 + fn * 16 + l15] =
                                f2bf(acc[fm][fn][r] + bias);
                }
            }
            __syncthreads();
            // store: quarter-wave owns one hd row; 16 lanes x 16B = 256-B runs
            const int hd0 = tid >> 4;         // 0..15 (+i*16)
            const int s8 = (tid & 15) * 8;
#pragma unroll
            for (int i = 0; i < 4; ++i) {
                const int hd = hd0 + i * 16;
                union { unsigned short h[8]; i32x4 v; } pk;
#pragma unroll
                for (int j = 0; j < 8; ++j) pk.h[j] = ldsT[(s8 + j) * 65 + hd];
                *(i32x4*)(Vt + (size_t)((bb * NH + hbase + p) * HDIM + hd) * SEQ +
                          sblock + s8) = pk.v;
            }
        }
    } else {
        // ---- Q/K epilogue: coalesced scatter [b][h][s][hd] (r9 verbatim) ----
#pragma unroll
        for (int fn = 0; fn < 4; ++fn) {
            const int col = n0 + wn * 64 + fn * 16 + l15;
            const int proj = col >> 10, rem = col & 1023;
            const int h = rem >> 6, hd = rem & 63;
            const float* bp = proj == 0 ? bq : bk;
            const float bias = bp[rem];
            const float scl = (proj == 0) ? 0.125f : 1.0f;
            unsigned short* dst = proj == 0 ? Qo : Ko;
#pragma unroll
            for (int fm = 0; fm < 4; ++fm) {
#pragma unroll
                for (int r = 0; r < 4; ++r) {
                    const int m = m0 + wm * 64 + fm * 16 + g * 4 + r;
                    const int bb = m >> 11, s = m & 2047;
                    dst[(size_t)((bb * NH + h) * SEQ + s) * HDIM + hd] =
                        f2bf((acc[fm][fn][r] + bias) * scl);
                }
            }
        }
    }
}

// ---------------- sliding-window flash attention (single-pass softmax) ----------------
// Round-3/9 version verbatim (~32us): Vt staged from global with b128 ops.
__global__ __launch_bounds__(256) void k_attn(const unsigned short* __restrict__ Qg,
                                              const unsigned short* __restrict__ Kg,
                                              const unsigned short* __restrict__ Vtg,
                                              const float* __restrict__ amask,
                                              float* __restrict__ out) {
    __shared__ unsigned short kl[224 * 64];      // swizzled rows (stride 128B)
    __shared__ unsigned short vl[64 * 224];      // swizzled rows (stride 448B)
    __shared__ unsigned short pl[4 * 16 * 160];  // per-wave 16x160 P tile
    const int bid0 = blockIdx.x;
    const int bid = (bid0 & 7) * 256 + (bid0 >> 3);  // XCD swizzle (2048 % 8 == 0)
    const int bh = bid >> 5, qb = bid & 31;
    const int b = bh >> 4, h = bh & 15;
    const int q0 = qb << 6;
    const int kstart = q0 - 144;
    const int tid = threadIdx.x, lane = tid & 63, w = tid >> 6;
    const int l15 = lane & 15, g = lane >> 4;

#pragma unroll
    for (int it = 0; it < 7; ++it) {
        const int c = it * 256 + tid;
        {  // K tile: row = key, 64 bf16 per row
            const int row = c >> 3, sl = c & 7;
            const int key = kstart + row;
            i32x4 v = {0, 0, 0, 0};
            if ((unsigned)key < (unsigned)SEQ)
                v = *(const i32x4*)(Kg + (size_t)(bh * SEQ + key) * HDIM + sl * 8);
            *(i32x4*)((char*)kl + ((row * 128 + sl * 16) ^ ((row & 7) << 4))) = v;
        }
        {  // Vt tile: row = hd, 224 keys per row
            const int row = c / 28, sl = c - row * 28;
            const int key0 = kstart + sl * 8;
            i32x4 v = {0, 0, 0, 0};
            if ((unsigned)key0 < (unsigned)SEQ)
                v = *(const i32x4*)(Vtg + (size_t)(bh * HDIM + row) * SEQ + key0);
            *(i32x4*)((char*)vl + ((row * 448 + sl * 16) ^ ((row & 7) << 4))) = v;
        }
    }
    const int iq = q0 + w * 16 + l15;
    const bf16x8 qf0 = *(const bf16x8*)(Qg + (size_t)(bh * SEQ + iq) * HDIM + g * 8);
    const bf16x8 qf1 = *(const bf16x8*)(Qg + (size_t)(bh * SEQ + iq) * HDIM + 32 + g * 8);
    __syncthreads();

    char* pbase = (char*)pl + w * 5120;
    const int swq = (l15 & 7) << 4;
    float s[40];

    // ---- phase 1: all QK^T chunks, masked scores into registers ----
    __builtin_amdgcn_s_setprio(1);
#pragma unroll
    for (int t = 0; t < 5; ++t) {
        const int tloc = w * 16 + t * 32;
        bf16x8 kf[2][2];
#pragma unroll
        for (int m = 0; m < 2; ++m) {
            const int row = tloc + m * 16 + l15;
            const int swz = (row & 7) << 4;
            kf[m][0] = *(const bf16x8*)((const char*)kl + ((row * 128 + g * 16) ^ swz));
            kf[m][1] = *(const bf16x8*)((const char*)kl + ((row * 128 + 64 + g * 16) ^ swz));
        }
        f32x4 sa0 = {0.f, 0.f, 0.f, 0.f}, sa1 = {0.f, 0.f, 0.f, 0.f};
        sa0 = MFMA16(kf[0][0], qf0, sa0);
        sa0 = MFMA16(kf[0][1], qf1, sa0);
        sa1 = MFMA16(kf[1][0], qf0, sa1);
        sa1 = MFMA16(kf[1][1], qf1, sa1);
#pragma unroll
        for (int f = 0; f < 2; ++f) {
            const int jb = kstart + tloc + f * 16 + g * 4;
            float4 m4 = {0.f, 0.f, 0.f, 0.f};
            if ((unsigned)jb < (unsigned)SEQ) m4 = *(const float4*)(amask + b * SEQ + jb);
            const float mvv[4] = {m4.x, m4.y, m4.z, m4.w};
#pragma unroll
            for (int r = 0; r < 4; ++r) {
                const int jg = jb + r;
                const float sc = (f == 0 ? sa0[r] : sa1[r]) + mvv[r];
                const bool ok = (jg >= 0) && (jg <= iq) && (iq - jg <= 128);
                s[t * 8 + f * 4 + r] = ok ? sc : -3.0e38f;
            }
        }
    }
    __builtin_amdgcn_s_setprio(0);

    // ---- phase 2: single softmax pass ----
    float tr[20];
#pragma unroll
    for (int i = 0; i < 20; ++i) tr[i] = fmaxf(s[i], s[i + 20]);
#pragma unroll
    for (int i = 0; i < 10; ++i) tr[i] = fmaxf(tr[i], tr[i + 10]);
#pragma unroll
    for (int i = 0; i < 5; ++i) tr[i] = fmaxf(tr[i], tr[i + 5]);
    float m = fmaxf(fmaxf(tr[0], tr[1]), fmaxf(tr[2], fmaxf(tr[3], tr[4])));
    m = fmaxf(m, __shfl_xor(m, 16));
    m = fmaxf(m, __shfl_xor(m, 32));  // always finite: key j==iq is in range

    float ls0 = 0.f, ls1 = 0.f, ls2 = 0.f, ls3 = 0.f;
#pragma unroll
    for (int i = 0; i < 40; i += 4) {
        float p0 = exp2f((s[i + 0] - m) * 1.44269504f);
        float p1 = exp2f((s[i + 1] - m) * 1.44269504f);
        float p2 = exp2f((s[i + 2] - m) * 1.44269504f);
        float p3 = exp2f((s[i + 3] - m) * 1.44269504f);
        s[i + 0] = p0; s[i + 1] = p1; s[i + 2] = p2; s[i + 3] = p3;
        ls0 += p0; ls1 += p1; ls2 += p2; ls3 += p3;
    }
    float l = (ls0 + ls1) + (ls2 + ls3);
    l += __shfl_xor(l, 16);
    l += __shfl_xor(l, 32);

    // ---- phase 3: write P (bf16) to per-wave LDS tile ----
#pragma unroll
    for (int t = 0; t < 5; ++t) {
#pragma unroll
        for (int f = 0; f < 2; ++f) {
            u16x4 pu = {f2bf(s[t * 8 + f * 4 + 0]), f2bf(s[t * 8 + f * 4 + 1]),
                        f2bf(s[t * 8 + f * 4 + 2]), f2bf(s[t * 8 + f * 4 + 3])};
            *(u16x4*)(pbase + ((l15 * 320 + t * 64 + f * 32 + g * 8) ^ swq)) = pu;
        }
    }
    asm volatile("s_waitcnt lgkmcnt(0)" ::: "memory");
    __builtin_amdgcn_sched_barrier(0);

    // ---- phase 4: PV, no rescaling ----
    f32x4 acc[4];
#pragma unroll
    for (int i = 0; i < 4; ++i) acc[i] = (f32x4){0.f, 0.f, 0.f, 0.f};
    __builtin_amdgcn_s_setprio(1);
#pragma unroll
    for (int t = 0; t < 5; ++t) {
        const int tloc = w * 16 + t * 32;
        const bf16x8 pf = *(const bf16x8*)(pbase + ((l15 * 320 + t * 64 + g * 16) ^ swq));
#pragma unroll
        for (int fn = 0; fn < 4; ++fn) {
            const int vrow = fn * 16 + l15;
            const bf16x8 vf = *(const bf16x8*)((const char*)vl +
                ((vrow * 448 + tloc * 2 + g * 16) ^ ((vrow & 7) << 4)));
            acc[fn] = MFMA16(pf, vf, acc[fn]);
        }
    }
    __builtin_amdgcn_s_setprio(0);

    float linv[4];
#pragma unroll
    for (int r = 0; r < 4; ++r) linv[r] = 1.0f / __shfl(l, g * 4 + r);
#pragma unroll
    for (int fn = 0; fn < 4; ++fn) {
#pragma unroll
        for (int r = 0; r < 4; ++r) {
            const int qrow = q0 + w * 16 + g * 4 + r;
            out[(size_t)(b * SEQ + qrow) * DMODEL + h * HDIM + fn * 16 + l15] =
                acc[fn][r] * linv[r];
        }
    }
}

extern "C" void kernel_launch(void* const* d_in, const int* in_sizes, int n_in,
                              void* d_out, int out_size, void* d_ws, size_t ws_size,
                              hipStream_t stream) {
    const float* hs = (const float*)d_in[0];
    const float* amask = (const float*)d_in[1];
    const float* wq = (const float*)d_in[2];
    const float* bq = (const float*)d_in[3];
    const float* wk = (const float*)d_in[4];
    const float* bk = (const float*)d_in[5];
    const float* wv = (const float*)d_in[6];
    const float* bv = (const float*)d_in[7];
    float* out = (float*)d_out;

    char* p = (char*)d_ws;
    unsigned short* Xbf = (unsigned short*)p;                          // 16 MB
    unsigned short* Wbf = (unsigned short*)(p + 16777216);             // 6 MB
    unsigned short* Qb = (unsigned short*)(p + 16777216 + 6291456);    // 16 MB
    unsigned short* Kb = Qb + 8388608;                                 // 16 MB
    unsigned short* Vtb = Kb + 8388608;                                // 16 MB (fresh: X live during k_qkv)

    k_cvt<<<11264, 256, 0, stream>>>(hs, wq, wk, wv, Xbf, Wbf);
    k_qkv<<<dim3(24, 64), 256, 0, stream>>>(Xbf, Wbf, bq, bk, bv, Qb, Kb, Vtb);
    k_attn<<<2048, 256, 0, stream>>>(Qb, Kb, Vtb, amask, out);
}